// Round 5
// baseline (279.253 us; speedup 1.0000x reference)
//
#include <hip/hip_runtime.h>

typedef unsigned short u16;
typedef unsigned int   u32;
typedef __attribute__((ext_vector_type(4))) float f32x4;
typedef __attribute__((ext_vector_type(8))) short short8;

#define MODEL_DIM 1024
#define SEQ 2048
#define BATCH 4
#define NHEAD 16
#define HDIM 64
#define MTOT (BATCH*SEQ)                       /* 8192 */
#define ELEMS ((size_t)MTOT*MODEL_DIM)         /* 8388608 */

__device__ __forceinline__ u16 f2bf(float f) {
    u32 u = __float_as_uint(f);
    u = (u + 0x7fffu + ((u >> 16) & 1u)) >> 16;   // RNE
    return (u16)u;
}
__device__ __forceinline__ u32 pack2(float a, float b) {
    return (u32)f2bf(a) | ((u32)f2bf(b) << 16);
}
__device__ __forceinline__ float bflo(u32 u) { return __uint_as_float(u << 16); }
__device__ __forceinline__ float bfhi(u32 u) { return __uint_as_float(u & 0xffff0000u); }
// packed RNE f32x2 -> bf16x2 (1 instr; no builtin on gfx950, T12 recipe)
__device__ __forceinline__ u32 cvtpk(float lo, float hi) {
    u32 r;
    asm("v_cvt_pk_bf16_f32 %0, %1, %2" : "=v"(r) : "v"(lo), "v"(hi));
    return r;
}

// async global->LDS 16B: wave-uniform LDS base + lane*16 (m97 pattern)
#define GLOAD16(g, l) __builtin_amdgcn_global_load_lds(                        \
        (const __attribute__((address_space(1))) unsigned int*)(g),            \
        (__attribute__((address_space(3))) unsigned int*)(l), 16, 0, 0)

// ---------------------------------------------------------------- cast X -> bf16
__global__ void cast_x_k(const float* __restrict__ X, u16* __restrict__ Xb) {
    size_t i = ((size_t)blockIdx.x * 256 + threadIdx.x) * 4;
    float4 v = *(const float4*)(X + i);
    uint2 o; o.x = pack2(v.x, v.y); o.y = pack2(v.z, v.w);
    *(uint2*)(Xb + i) = o;
}

// ---------------------------------------------- W[k][n] fp32 -> Wt[w][n][k] bf16
__global__ void transw_k(const float* __restrict__ Wq, const float* __restrict__ Wk,
                         const float* __restrict__ Wv, const float* __restrict__ Wo,
                         u16* __restrict__ Wt) {
    __shared__ float tile[32][33];
    int z = blockIdx.z;
    const float* W = (z == 0) ? Wq : (z == 1) ? Wk : (z == 2) ? Wv : Wo;
    int k0 = blockIdx.y * 32, n0 = blockIdx.x * 32;
    int x = threadIdx.x, y = threadIdx.y;               // 32 x 8
    for (int i = 0; i < 4; ++i)
        tile[y + i * 8][x] = W[(size_t)(k0 + y + i * 8) * MODEL_DIM + n0 + x];
    __syncthreads();
    u16* out = Wt + ((size_t)z << 20);
    for (int i = 0; i < 4; ++i)
        out[(size_t)(n0 + y + i * 8) * MODEL_DIM + k0 + x] = f2bf(tile[x][y + i * 8]);
}

// ----------------------------------------------------------------- GEMM 128x128
// m97 structure: BK=32, linear LDS [128][32], global_load_lds width-16 staging.
// MODE 0: A=Xb, N=3072: writes Qb,Kb,Vb (bf16, +bias). RoPE fused into the
//         epilogue for Q/K regions (rotation on f32 acc, single bf16 rounding;
//         softmax scale 0.125 folded into Q).
// MODE 1: A=Ob, N=1024: writes fp32 out + bo.
template<int MODE>
__global__ __launch_bounds__(256) void gemm128_k(
        const u16* __restrict__ A, const u16* __restrict__ Wt,
        u16* __restrict__ Qb, u16* __restrict__ Kb, u16* __restrict__ Vb,
        float* __restrict__ outO,
        const float* __restrict__ bq, const float* __restrict__ bk,
        const float* __restrict__ bv, const float* __restrict__ bo) {
    __shared__ __align__(16) u16 As[128 * 32];
    __shared__ __align__(16) u16 Bs[128 * 32];
    const int tid  = threadIdx.x;
    const int wave = tid >> 6, lane = tid & 63;
    const int l15  = lane & 15, quad = lane >> 4;
    const int wm = (wave & 1) * 64, wn = (wave >> 1) * 64;
    const int m0 = blockIdx.x * 128;
    const int n0 = blockIdx.y * 128;

    const u16* bbase;
    if (MODE == 0) {
        int region = n0 >> 10;
        bbase = Wt + ((size_t)region << 20) + (size_t)(n0 & 1023) * MODEL_DIM;
    } else {
        bbase = Wt + ((size_t)3 << 20) + (size_t)n0 * MODEL_DIM;
    }
    const u16* abase = A + (size_t)m0 * MODEL_DIM;

    f32x4 acc[4][4] = {};
    // staging: thread tid owns global row r0 = tid>>2, 16B k-chunk kc0 = (tid&3)*8.
    // LDS dest byte tid*16 == r0*64 + (tid&3)*16  -> linear [128][32] layout.
    const int r0 = tid >> 2, kc0 = (tid & 3) * 8;
    const u16* ga = abase + (size_t)r0 * MODEL_DIM + kc0;
    const u16* gb = bbase + (size_t)r0 * MODEL_DIM + kc0;
    u16* la0 = &As[tid * 8];
    u16* la1 = &As[2048 + tid * 8];          // rows 64..127
    u16* lb0 = &Bs[tid * 8];
    u16* lb1 = &Bs[2048 + tid * 8];

    for (int k0 = 0; k0 < MODEL_DIM; k0 += 32) {
        GLOAD16(ga + k0, la0);
        GLOAD16(ga + (size_t)64 * MODEL_DIM + k0, la1);
        GLOAD16(gb + k0, lb0);
        GLOAD16(gb + (size_t)64 * MODEL_DIM + k0, lb1);
        __syncthreads();                     // drains vmcnt: tiles resident
        short8 af[4], bf[4];
        for (int i = 0; i < 4; ++i)
            af[i] = *(const short8*)(&As[(wm + i * 16 + l15) * 32 + quad * 8]);
        for (int i = 0; i < 4; ++i)
            bf[i] = *(const short8*)(&Bs[(wn + i * 16 + l15) * 32 + quad * 8]);
        for (int mi = 0; mi < 4; ++mi)
            for (int ni = 0; ni < 4; ++ni)
                acc[mi][ni] = __builtin_amdgcn_mfma_f32_16x16x32_bf16(
                                  af[mi], bf[ni], acc[mi][ni], 0, 0, 0);
        __syncthreads();                     // ds_reads retired before next stage
    }

    // epilogue: C/D layout col=lane&15, row=quad*4+reg
    if (MODE == 0) {
        const int region = n0 >> 10;
        const float* bias = (region == 0) ? bq : (region == 1) ? bk : bv;
        u16* dst = (region == 0) ? Qb : (region == 1) ? Kb : Vb;
        if (region < 2) {
            // ---- fused RoPE on f32 acc. pair (c even, c odd) lives in lane
            // pair (l15, l15^1); inv_freq depends only on c>>1 (same for pair).
            const float qsc = (region == 0) ? 0.125f : 1.0f;  // 1/sqrt(64) into Q
            const float cfr = -0.017989922f;                  // -ln(10000)/512
            float invf[4];
            for (int ni = 0; ni < 4; ++ni) {
                int c = (n0 + wn + ni * 16 + l15) & 1023;
                invf[ni] = __expf((float)(c >> 1) * cfr);
            }
            const float sgn = (l15 & 1) ? 1.0f : -1.0f;  // even: x1*cs - x2*sn
            for (int mi = 0; mi < 4; ++mi)
                for (int r = 0; r < 4; ++r) {
                    size_t rowg = (size_t)(m0 + wm + mi * 16 + quad * 4 + r);
                    float fs = (float)(int)(rowg & 2047);
                    for (int ni = 0; ni < 4; ++ni) {
                        int c = (n0 + wn + ni * 16 + l15) & 1023;
                        float v = acc[mi][ni][r] + bias[c];
                        float mate = __shfl_xor(v, 1, 64);
                        float sn, cs;
                        __sincosf(fs * invf[ni], &sn, &cs);
                        float o = (v * cs + sgn * mate * sn) * qsc;
                        dst[rowg * MODEL_DIM + c] = f2bf(o);
                    }
                }
        } else {
            for (int mi = 0; mi < 4; ++mi)
                for (int r = 0; r < 4; ++r) {
                    size_t rowg = (size_t)(m0 + wm + mi * 16 + quad * 4 + r);
                    for (int ni = 0; ni < 4; ++ni) {
                        int col = (n0 + wn + ni * 16 + l15) & 1023;
                        dst[rowg * MODEL_DIM + col] = f2bf(acc[mi][ni][r] + bias[col]);
                    }
                }
        }
    } else {
        for (int mi = 0; mi < 4; ++mi)
            for (int r = 0; r < 4; ++r) {
                size_t rowg = (size_t)(m0 + wm + mi * 16 + quad * 4 + r);
                for (int ni = 0; ni < 4; ++ni) {
                    int colg = n0 + wn + ni * 16 + l15;
                    outO[rowg * MODEL_DIM + colg] = acc[mi][ni][r] + bo[colg];
                }
            }
    }
}

// ---------------------------- V [b*S][h*64+d] bf16  ->  VT32[(bh*64+d)][s-pairs]
__global__ __launch_bounds__(256) void vt_k(const u32* __restrict__ Vb32,
                                            u32* __restrict__ VT32) {
    __shared__ u32 tile[64 * 33];
    int bh = blockIdx.y, b = bh >> 4, h = bh & 15;
    int s0 = blockIdx.x * 64;
    int t = threadIdx.x;
    for (int it = 0; it < 8; ++it) {
        int idx = it * 256 + t;
        int s = idx >> 5, dc = idx & 31;     // dc: u32 = 2 dims
        tile[s * 33 + dc] = Vb32[(size_t)(b * SEQ + s0 + s) * (MODEL_DIM / 2)
                                 + h * (HDIM / 2) + dc];
    }
    __syncthreads();
    for (int it = 0; it < 8; ++it) {
        int idx = it * 256 + t;
        int d = idx >> 5, sc = idx & 31;     // sc: u32 = 2 seq positions
        u32 w0 = tile[(2 * sc) * 33 + (d >> 1)];
        u32 w1 = tile[(2 * sc + 1) * 33 + (d >> 1)];
        u32 val = (d & 1) ? ((w0 >> 16) | (w1 & 0xffff0000u))
                          : ((w0 & 0xffffu) | (w1 << 16));
        VT32[(size_t)(bh * HDIM + d) * (SEQ / 2) + (s0 >> 1) + sc] = val;
    }
}

// ------------------------------------------------------- flash attention (causal)
// grid (8,16,4); 256 thr = 4 waves; wave owns 32 q-rows of the active q-tile.
// Causal pair-balancing: block j runs q-tile (15-j) then q-tile j (34 iters/block).
// T14 pipeline: double-buffered K/V LDS, prefetch-to-regs after the single
// barrier/iter (continuous buffer parity spans both passes -> no extra barrier).
// T13 defer-max; v_cvt_pk_bf16_f32 for P/O packing.
__global__ __launch_bounds__(256, 2) void attn_k(const u16* __restrict__ Qb,
                                                 const u16* __restrict__ Kb,
                                                 const u32* __restrict__ VT32,
                                                 u16* __restrict__ Ob) {
    __shared__ __align__(16) u16 Ks[2][64 * 64];   // [key][dim], chunk-XOR swizzle
    __shared__ __align__(16) u16 Vs[2][64 * 64];   // [d][key],   chunk-XOR swizzle
    __shared__ __align__(16) u16 Pl[4 * 32 * 72];  // per-wave P^T [q][key], pad 8
    const int tid  = threadIdx.x;
    const int wave = tid >> 6, lane = tid & 63;
    const int l15  = lane & 15, quad = lane >> 4;
    const int j = blockIdx.x;                      // 0..7 pair index
    const int h = blockIdx.y, b = blockIdx.z;
    u16* pw = &Pl[wave * 32 * 72];

    // staging geometry (constant per thread): rows key0 and key0+32, 16B chunk c
    const int key0 = tid >> 3;                     // 0..31
    const int c8   = (tid & 7) * 8;                // u16 units
    const int c4   = (tid & 7) * 4;                // u32 units (VT rows)
    const int lko  = key0 * 64 + (((tid & 7) ^ (key0 & 7)) * 8);   // LDS dst
    const u16* kgp = Kb + (size_t)(b * SEQ) * MODEL_DIM + h * HDIM;
    const u32* vgp = VT32 + (size_t)((b * NHEAD + h) * HDIM) * (SEQ / 2);

    int bufc = 0;                                  // buffer parity, spans passes
    for (int pp = 0; pp < 2; ++pp) {
        const int qt = pp ? j : 15 - j;            // heavy tile first
        const int q0 = qt * 128;
        const int qbase = q0 + wave * 32;

        // Q B-frags (n=q=lane&15, k=dim=quad*8+jj), already scaled by 0.125
        short8 qfr[2][2];
        for (int qf = 0; qf < 2; ++qf)
            for (int ks = 0; ks < 2; ++ks)
                qfr[qf][ks] = *(const short8*)(Qb
                    + (size_t)(b * SEQ + qbase + qf * 16 + l15) * MODEL_DIM
                    + h * HDIM + ks * 32 + quad * 8);

        float m_i[2] = {-1e30f, -1e30f}, l_i[2] = {0.f, 0.f};
        f32x4 o_acc[4][2] = {};                    // [dt][qf]

        const int nkt = (q0 + 128) >> 6;
        // prologue prefetch (kt = 0)
        uint4 kr0 = *(const uint4*)(kgp + (size_t)key0 * MODEL_DIM + c8);
        uint4 kr1 = *(const uint4*)(kgp + (size_t)(key0 + 32) * MODEL_DIM + c8);
        uint4 vr0 = *(const uint4*)(vgp + (size_t)key0 * (SEQ / 2) + c4);
        uint4 vr1 = *(const uint4*)(vgp + (size_t)(key0 + 32) * (SEQ / 2) + c4);

        for (int kt = 0; kt < nkt; ++kt) {
            const int k0 = kt * 64;
            u16* ksb = Ks[bufc];
            u16* vsb = Vs[bufc];
            *(uint4*)(&ksb[lko])        = kr0;     // drain prefetched tile -> LDS
            *(uint4*)(&ksb[lko + 2048]) = kr1;
            *(uint4*)(&vsb[lko])        = vr0;
            *(uint4*)(&vsb[lko + 2048]) = vr1;
            __syncthreads();                       // single barrier per iter

            if (kt + 1 < nkt) {                    // prefetch next tile (hidden
                const int kn = k0 + 64;            //  under this tile's compute)
                kr0 = *(const uint4*)(kgp + (size_t)(kn + key0) * MODEL_DIM + c8);
                kr1 = *(const uint4*)(kgp + (size_t)(kn + key0 + 32) * MODEL_DIM + c8);
                vr0 = *(const uint4*)(vgp + (size_t)key0 * (SEQ / 2) + (kn >> 1) + c4);
                vr1 = *(const uint4*)(vgp + (size_t)(key0 + 32) * (SEQ / 2)
                                      + (kn >> 1) + c4);
            }

            if (k0 <= qbase + 31) {                // wave has live rows this tile
                // S^T = K Q^T
                f32x4 s[4][2] = {};
                for (int ks = 0; ks < 2; ++ks) {
                    short8 kfr[4];
                    for (int kf = 0; kf < 4; ++kf)
                        kfr[kf] = *(const short8*)(&ksb[(kf * 16 + l15) * 64
                                      + (((ks * 4 + quad) ^ (l15 & 7)) * 8)]);
                    for (int kf = 0; kf < 4; ++kf)
                        for (int qf = 0; qf < 2; ++qf)
                            s[kf][qf] = __builtin_amdgcn_mfma_f32_16x16x32_bf16(
                                            kfr[kf], qfr[qf][ks], s[kf][qf], 0, 0, 0);
                }
                for (int qf = 0; qf < 2; ++qf) {
                    int qg = qbase + qf * 16 + l15;
                    if (k0 + 63 > qbase + qf * 16) {   // diagonal tile: apply mask
                        for (int kf = 0; kf < 4; ++kf)
                            for (int r = 0; r < 4; ++r)
                                if (k0 + kf * 16 + quad * 4 + r > qg)
                                    s[kf][qf][r] = -1e30f;
                    }
                    float rmax = s[0][qf][0];
                    for (int kf = 0; kf < 4; ++kf)
                        for (int r = 0; r < 4; ++r) rmax = fmaxf(rmax, s[kf][qf][r]);
                    rmax = fmaxf(rmax, __shfl_xor(rmax, 16, 64));
                    rmax = fmaxf(rmax, __shfl_xor(rmax, 32, 64));
                    // T13 defer-max: skip rescale unless some row grew > +8
                    if (!__all(rmax <= m_i[qf] + 8.0f)) {
                        float mn = fmaxf(m_i[qf], rmax);
                        float alpha = __expf(m_i[qf] - mn);
                        m_i[qf] = mn;
                        l_i[qf] *= alpha;
                        for (int dt = 0; dt < 4; ++dt)
                            for (int r = 0; r < 4; ++r) o_acc[dt][qf][r] *= alpha;
                    }
                    float mref = m_i[qf];
                    float psum = 0.f;
                    for (int kf = 0; kf < 4; ++kf)
                        for (int r = 0; r < 4; ++r) {
                            float p = __expf(s[kf][qf][r] - mref);
                            s[kf][qf][r] = p;
                            psum += p;
                        }
                    psum += __shfl_xor(psum, 16, 64);
                    psum += __shfl_xor(psum, 32, 64);
                    l_i[qf] += psum;
                    for (int kf = 0; kf < 4; ++kf) {   // P^T -> LDS (uint2)
                        uint2 w;
                        w.x = cvtpk(s[kf][qf][0], s[kf][qf][1]);
                        w.y = cvtpk(s[kf][qf][2], s[kf][qf][3]);
                        *(uint2*)(&pw[(qf * 16 + l15) * 72 + kf * 16 + quad * 4]) = w;
                    }
                }
                // O^T += V^T P^T
                for (int ks = 0; ks < 2; ++ks) {
                    short8 pfr[2], vfr[4];
                    for (int qf = 0; qf < 2; ++qf)
                        pfr[qf] = *(const short8*)(&pw[(qf * 16 + l15) * 72
                                                       + ks * 32 + quad * 8]);
                    for (int dt = 0; dt < 4; ++dt)
                        vfr[dt] = *(const short8*)(&vsb[(dt * 16 + l15) * 64
                                      + (((ks * 4 + quad) ^ (l15 & 7)) * 8)]);
                    for (int dt = 0; dt < 4; ++dt)
                        for (int qf = 0; qf < 2; ++qf)
                            o_acc[dt][qf] = __builtin_amdgcn_mfma_f32_16x16x32_bf16(
                                                vfr[dt], pfr[qf], o_acc[dt][qf], 0, 0, 0);
                }
            }
            bufc ^= 1;
        }

        // O^T C-layout: q = lane&15, d = quad*4+r (within dt)
        for (int qf = 0; qf < 2; ++qf) {
            float rl = 1.f / l_i[qf];
            int q = qbase + qf * 16 + l15;
            for (int dt = 0; dt < 4; ++dt) {
                uint2 w;
                w.x = cvtpk(o_acc[dt][qf][0] * rl, o_acc[dt][qf][1] * rl);
                w.y = cvtpk(o_acc[dt][qf][2] * rl, o_acc[dt][qf][3] * rl);
                *(uint2*)(&Ob[(size_t)(b * SEQ + q) * MODEL_DIM
                              + h * HDIM + dt * 16 + quad * 4]) = w;
            }
        }
    }
}

// --------------------------------------------------------------------- launcher
extern "C" void kernel_launch(void* const* d_in, const int* in_sizes, int n_in,
                              void* d_out, int out_size, void* d_ws, size_t ws_size,
                              hipStream_t stream) {
    const float* X  = (const float*)d_in[0];
    const float* Wq = (const float*)d_in[1];
    const float* bq = (const float*)d_in[2];
    const float* Wk = (const float*)d_in[3];
    const float* bk = (const float*)d_in[4];
    const float* Wv = (const float*)d_in[5];
    const float* bv = (const float*)d_in[6];
    const float* Wo = (const float*)d_in[7];
    const float* bo = (const float*)d_in[8];
    float* out = (float*)d_out;

    // ws: [Xb/Ob 16.78M][Wt 8.39M][Qb 16.78M][Kb 16.78M][Vb 16.78M][VT 16.78M]=92.3M
    char* ws = (char*)d_ws;
    u16* Xb   = (u16*)ws;                       // aliased by Ob after QKV GEMM
    u16* Ob   = (u16*)ws;
    u16* Wt   = (u16*)(ws + 16777216);
    u16* Qb   = (u16*)(ws + 25165824);
    u16* Kb   = (u16*)(ws + 41943040);
    u16* Vb   = (u16*)(ws + 58720256);
    u32* VT32 = (u32*)(ws + 75497472);

    cast_x_k<<<dim3(ELEMS / 1024), dim3(256), 0, stream>>>(X, Xb);
    transw_k<<<dim3(32, 32, 4), dim3(32, 8), 0, stream>>>(Wq, Wk, Wv, Wo, Wt);
    gemm128_k<0><<<dim3(64, 24), dim3(256), 0, stream>>>(Xb, Wt, Qb, Kb, Vb, nullptr,
                                                         bq, bk, bv, nullptr);
    vt_k<<<dim3(32, 64), dim3(256), 0, stream>>>((const u32*)Vb, VT32);
    attn_k<<<dim3(8, 16, 4), dim3(256), 0, stream>>>(Qb, Kb, VT32, Ob);
    gemm128_k<1><<<dim3(64, 8), dim3(256), 0, stream>>>(Ob, Wt, nullptr, nullptr,
                                                        nullptr, out,
                                                        nullptr, nullptr, nullptr, bo);
}

// Round 6
// 271.557 us; speedup vs baseline: 1.0283x; 1.0283x over previous
//
#include <hip/hip_runtime.h>

typedef unsigned short u16;
typedef unsigned int   u32;
typedef __attribute__((ext_vector_type(4))) float f32x4;
typedef __attribute__((ext_vector_type(8))) short short8;

#define MODEL_DIM 1024
#define SEQ 2048
#define BATCH 4
#define NHEAD 16
#define HDIM 64
#define MTOT (BATCH*SEQ)                       /* 8192 */
#define ELEMS ((size_t)MTOT*MODEL_DIM)         /* 8388608 */

__device__ __forceinline__ u16 f2bf(float f) {
    u32 u = __float_as_uint(f);
    u = (u + 0x7fffu + ((u >> 16) & 1u)) >> 16;   // RNE
    return (u16)u;
}
__device__ __forceinline__ u32 pack2(float a, float b) {
    return (u32)f2bf(a) | ((u32)f2bf(b) << 16);
}
// packed RNE f32x2 -> bf16x2 (1 instr; no builtin on gfx950, T12 recipe)
__device__ __forceinline__ u32 cvtpk(float lo, float hi) {
    u32 r;
    asm("v_cvt_pk_bf16_f32 %0, %1, %2" : "=v"(r) : "v"(lo), "v"(hi));
    return r;
}
// raw 2^x (v_exp_f32); softmax runs in log2 domain (log2e folded into Q scale)
__device__ __forceinline__ float exp2a(float x) {
    float r;
    asm("v_exp_f32 %0, %1" : "=v"(r) : "v"(x));
    return r;
}

// async global->LDS 16B: wave-uniform LDS base + lane*16 (m97 pattern)
#define GLOAD16(g, l) __builtin_amdgcn_global_load_lds(                        \
        (const __attribute__((address_space(1))) unsigned int*)(g),            \
        (__attribute__((address_space(3))) unsigned int*)(l), 16, 0, 0)

// ------------------------- prep: cast X -> bf16  +  W[k][n] fp32 -> Wt[n][k] bf16
// flat grid: blocks [0, 8192) cast; blocks [8192, 12288) transpose W.
__global__ __launch_bounds__(256) void prep_k(const float* __restrict__ X,
                                              u16* __restrict__ Xb,
                                              const float* __restrict__ Wq,
                                              const float* __restrict__ Wk,
                                              const float* __restrict__ Wv,
                                              const float* __restrict__ Wo,
                                              u16* __restrict__ Wt) {
    const int bid = blockIdx.x, t = threadIdx.x;
    if (bid < 8192) {
        size_t i = ((size_t)bid * 256 + t) * 4;
        float4 v = *(const float4*)(X + i);
        uint2 o; o.x = pack2(v.x, v.y); o.y = pack2(v.z, v.w);
        *(uint2*)(Xb + i) = o;
        return;
    }
    __shared__ float tile[32][33];
    const int bid2 = bid - 8192;
    const int z = bid2 >> 10, rem = bid2 & 1023;
    const int by = rem >> 5, bx = rem & 31;
    const float* W = (z == 0) ? Wq : (z == 1) ? Wk : (z == 2) ? Wv : Wo;
    const int k0 = by * 32, n0 = bx * 32;
    const int x = t & 31, y = t >> 5;                   // 32 x 8
    for (int i = 0; i < 4; ++i)
        tile[y + i * 8][x] = W[(size_t)(k0 + y + i * 8) * MODEL_DIM + n0 + x];
    __syncthreads();
    u16* out = Wt + ((size_t)z << 20);
    for (int i = 0; i < 4; ++i)
        out[(size_t)(n0 + y + i * 8) * MODEL_DIM + k0 + x] = f2bf(tile[x][y + i * 8]);
}

// ----------------------------------------------------------------- GEMM 128x128
// m97 structure: BK=32, linear LDS [128][32], global_load_lds width-16 staging.
// MODE 0: A=Xb, N=3072. region 0/1 (Q/K): fused RoPE epilogue -> Qb/Kb bf16
//         (Q also scaled by 0.125*log2e for exp2-domain softmax).
//         region 2 (V): epilogue transposes via LDS and writes VT32 directly.
// MODE 1: A=Ob, N=1024: writes fp32 out + bo.
template<int MODE>
__global__ __launch_bounds__(256) void gemm128_k(
        const u16* __restrict__ A, const u16* __restrict__ Wt,
        u16* __restrict__ Qb, u16* __restrict__ Kb, u32* __restrict__ VT,
        float* __restrict__ outO,
        const float* __restrict__ bq, const float* __restrict__ bk,
        const float* __restrict__ bv, const float* __restrict__ bo) {
    // union: As|Bs (16KB) during K-loop; Ts [128][130] (33KB) for V transpose
    __shared__ __align__(16) u16 smem[(MODE == 0) ? 128 * 130 : 128 * 64];
    u16* As = smem;
    u16* Bs = smem + 4096;
    const int tid  = threadIdx.x;
    const int wave = tid >> 6, lane = tid & 63;
    const int l15  = lane & 15, quad = lane >> 4;
    const int wm = (wave & 1) * 64, wn = (wave >> 1) * 64;
    const int m0 = blockIdx.x * 128;
    const int n0 = blockIdx.y * 128;

    const u16* bbase;
    if (MODE == 0) {
        int region = n0 >> 10;
        bbase = Wt + ((size_t)region << 20) + (size_t)(n0 & 1023) * MODEL_DIM;
    } else {
        bbase = Wt + ((size_t)3 << 20) + (size_t)n0 * MODEL_DIM;
    }
    const u16* abase = A + (size_t)m0 * MODEL_DIM;

    f32x4 acc[4][4] = {};
    // staging: thread tid owns global row r0 = tid>>2, 16B k-chunk kc0 = (tid&3)*8.
    // LDS dest byte tid*16 == r0*64 + (tid&3)*16  -> linear [128][32] layout.
    const int r0 = tid >> 2, kc0 = (tid & 3) * 8;
    const u16* ga = abase + (size_t)r0 * MODEL_DIM + kc0;
    const u16* gb = bbase + (size_t)r0 * MODEL_DIM + kc0;
    u16* la0 = &As[tid * 8];
    u16* la1 = &As[2048 + tid * 8];          // rows 64..127
    u16* lb0 = &Bs[tid * 8];
    u16* lb1 = &Bs[2048 + tid * 8];

    for (int k0 = 0; k0 < MODEL_DIM; k0 += 32) {
        GLOAD16(ga + k0, la0);
        GLOAD16(ga + (size_t)64 * MODEL_DIM + k0, la1);
        GLOAD16(gb + k0, lb0);
        GLOAD16(gb + (size_t)64 * MODEL_DIM + k0, lb1);
        __syncthreads();                     // drains vmcnt: tiles resident
        short8 af[4], bf[4];
        for (int i = 0; i < 4; ++i)
            af[i] = *(const short8*)(&As[(wm + i * 16 + l15) * 32 + quad * 8]);
        for (int i = 0; i < 4; ++i)
            bf[i] = *(const short8*)(&Bs[(wn + i * 16 + l15) * 32 + quad * 8]);
        for (int mi = 0; mi < 4; ++mi)
            for (int ni = 0; ni < 4; ++ni)
                acc[mi][ni] = __builtin_amdgcn_mfma_f32_16x16x32_bf16(
                                  af[mi], bf[ni], acc[mi][ni], 0, 0, 0);
        __syncthreads();                     // ds_reads retired before next stage
    }

    // epilogue: C/D layout col=lane&15, row=quad*4+reg
    if (MODE == 0) {
        const int region = n0 >> 10;
        if (region < 2) {
            // ---- fused RoPE on f32 acc. pair (c even, c odd) lives in lane
            // pair (l15, l15^1); inv_freq depends only on c>>1 (same for pair).
            const float* bias = (region == 0) ? bq : bk;
            u16* dst = (region == 0) ? Qb : Kb;
            // Q: 1/sqrt(64) * log2(e) folded in (softmax runs in exp2 domain)
            const float qsc = (region == 0) ? 0.125f * 1.44269504f : 1.0f;
            const float cfr = -0.017989922f;                  // -ln(10000)/512
            float invf[4];
            for (int ni = 0; ni < 4; ++ni) {
                int c = (n0 + wn + ni * 16 + l15) & 1023;
                invf[ni] = __expf((float)(c >> 1) * cfr);
            }
            const float sgn = (l15 & 1) ? 1.0f : -1.0f;  // even: x1*cs - x2*sn
            for (int mi = 0; mi < 4; ++mi)
                for (int r = 0; r < 4; ++r) {
                    size_t rowg = (size_t)(m0 + wm + mi * 16 + quad * 4 + r);
                    float fs = (float)(int)(rowg & 2047);
                    for (int ni = 0; ni < 4; ++ni) {
                        int c = (n0 + wn + ni * 16 + l15) & 1023;
                        float v = acc[mi][ni][r] + bias[c];
                        float mate = __shfl_xor(v, 1, 64);
                        float sn, cs;
                        __sincosf(fs * invf[ni], &sn, &cs);
                        float o = (v * cs + sgn * mate * sn) * qsc;
                        dst[rowg * MODEL_DIM + c] = f2bf(o);
                    }
                }
        } else {
            // ---- V: transpose via LDS, write VT32 directly (vt_k fused away).
            // Ts[col_local][row_local], stride 130 (bank-spread). Safe to reuse
            // smem: K-loop's final barrier retired all As/Bs reads.
            u16* Ts = smem;
            for (int mi = 0; mi < 4; ++mi)
                for (int r = 0; r < 4; ++r) {
                    int rl = wm + mi * 16 + quad * 4 + r;
                    for (int ni = 0; ni < 4; ++ni) {
                        int cl = wn + ni * 16 + l15;
                        Ts[cl * 130 + rl] = f2bf(acc[mi][ni][r]
                                                 + bv[(n0 & 1023) + cl]);
                    }
                }
            __syncthreads();
            const int b_ = m0 >> 11;
            const int srow0 = (m0 & 2047) >> 1;
            const int h0 = (n0 & 1023) >> 6;
            u32* vtb = VT + (size_t)((b_ * NHEAD + h0) * HDIM) * (SEQ / 2);
            for (int it = 0; it < 32; ++it) {
                int idx = it * 256 + tid;
                int dl = idx >> 6, sc = idx & 63;       // dl 0..127 spans 2 heads
                u32 val = *(const u32*)&Ts[dl * 130 + 2 * sc];  // [even|odd<<16]
                vtb[(size_t)dl * (SEQ / 2) + srow0 + sc] = val;
            }
        }
    } else {
        for (int mi = 0; mi < 4; ++mi)
            for (int r = 0; r < 4; ++r) {
                size_t rowg = (size_t)(m0 + wm + mi * 16 + quad * 4 + r);
                for (int ni = 0; ni < 4; ++ni) {
                    int colg = n0 + wn + ni * 16 + l15;
                    outO[rowg * MODEL_DIM + colg] = acc[mi][ni][r] + bo[colg];
                }
            }
    }
}

// ------------------------------------------------------- flash attention (causal)
// grid (8,16,4); 256 thr = 4 waves; wave owns 32 q-rows of the active q-tile.
// Causal pair-balancing: block j runs q-tile (15-j) then q-tile j (34 iters/block).
// T14 pipeline: double-buffered K/V LDS, single barrier/iter. T13 defer-max.
// Softmax in log2 domain: Q pre-scaled by 0.125*log2e, exp -> raw v_exp_f32.
__global__ __launch_bounds__(256, 2) void attn_k(const u16* __restrict__ Qb,
                                                 const u16* __restrict__ Kb,
                                                 const u32* __restrict__ VT32,
                                                 u16* __restrict__ Ob) {
    __shared__ __align__(16) u16 Ks[2][64 * 64];   // [key][dim], chunk-XOR swizzle
    __shared__ __align__(16) u16 Vs[2][64 * 64];   // [d][key],   chunk-XOR swizzle
    __shared__ __align__(16) u16 Pl[4 * 32 * 72];  // per-wave P^T [q][key], pad 8
    const int tid  = threadIdx.x;
    const int wave = tid >> 6, lane = tid & 63;
    const int l15  = lane & 15, quad = lane >> 4;
    const int j = blockIdx.x;                      // 0..7 pair index
    const int h = blockIdx.y, b = blockIdx.z;
    u16* pw = &Pl[wave * 32 * 72];

    // staging geometry (constant per thread): rows key0 and key0+32, 16B chunk c
    const int key0 = tid >> 3;                     // 0..31
    const int c8   = (tid & 7) * 8;                // u16 units
    const int c4   = (tid & 7) * 4;                // u32 units (VT rows)
    const int lko  = key0 * 64 + (((tid & 7) ^ (key0 & 7)) * 8);   // LDS dst
    const u16* kgp = Kb + (size_t)(b * SEQ) * MODEL_DIM + h * HDIM;
    const u32* vgp = VT32 + (size_t)((b * NHEAD + h) * HDIM) * (SEQ / 2);

    int bufc = 0;                                  // buffer parity, spans passes
    for (int pp = 0; pp < 2; ++pp) {
        const int qt = pp ? j : 15 - j;            // heavy tile first
        const int q0 = qt * 128;
        const int qbase = q0 + wave * 32;

        // Q B-frags (n=q=lane&15, k=dim=quad*8+jj), pre-scaled 0.125*log2e
        short8 qfr[2][2];
        for (int qf = 0; qf < 2; ++qf)
            for (int ks = 0; ks < 2; ++ks)
                qfr[qf][ks] = *(const short8*)(Qb
                    + (size_t)(b * SEQ + qbase + qf * 16 + l15) * MODEL_DIM
                    + h * HDIM + ks * 32 + quad * 8);

        float m_i[2] = {-1e30f, -1e30f}, l_i[2] = {0.f, 0.f};
        f32x4 o_acc[4][2] = {};                    // [dt][qf]

        const int nkt = (q0 + 128) >> 6;
        // prologue prefetch (kt = 0)
        uint4 kr0 = *(const uint4*)(kgp + (size_t)key0 * MODEL_DIM + c8);
        uint4 kr1 = *(const uint4*)(kgp + (size_t)(key0 + 32) * MODEL_DIM + c8);
        uint4 vr0 = *(const uint4*)(vgp + (size_t)key0 * (SEQ / 2) + c4);
        uint4 vr1 = *(const uint4*)(vgp + (size_t)(key0 + 32) * (SEQ / 2) + c4);

        for (int kt = 0; kt < nkt; ++kt) {
            const int k0 = kt * 64;
            u16* ksb = Ks[bufc];
            u16* vsb = Vs[bufc];
            *(uint4*)(&ksb[lko])        = kr0;     // drain prefetched tile -> LDS
            *(uint4*)(&ksb[lko + 2048]) = kr1;
            *(uint4*)(&vsb[lko])        = vr0;
            *(uint4*)(&vsb[lko + 2048]) = vr1;
            __syncthreads();                       // single barrier per iter

            if (kt + 1 < nkt) {                    // prefetch next tile (hidden
                const int kn = k0 + 64;            //  under this tile's compute)
                kr0 = *(const uint4*)(kgp + (size_t)(kn + key0) * MODEL_DIM + c8);
                kr1 = *(const uint4*)(kgp + (size_t)(kn + key0 + 32) * MODEL_DIM + c8);
                vr0 = *(const uint4*)(vgp + (size_t)key0 * (SEQ / 2) + (kn >> 1) + c4);
                vr1 = *(const uint4*)(vgp + (size_t)(key0 + 32) * (SEQ / 2)
                                      + (kn >> 1) + c4);
            }

            if (k0 <= qbase + 31) {                // wave has live rows this tile
                // S^T = K Q^T
                f32x4 s[4][2] = {};
                for (int ks = 0; ks < 2; ++ks) {
                    short8 kfr[4];
                    for (int kf = 0; kf < 4; ++kf)
                        kfr[kf] = *(const short8*)(&ksb[(kf * 16 + l15) * 64
                                      + (((ks * 4 + quad) ^ (l15 & 7)) * 8)]);
                    for (int kf = 0; kf < 4; ++kf)
                        for (int qf = 0; qf < 2; ++qf)
                            s[kf][qf] = __builtin_amdgcn_mfma_f32_16x16x32_bf16(
                                            kfr[kf], qfr[qf][ks], s[kf][qf], 0, 0, 0);
                }
                for (int qf = 0; qf < 2; ++qf) {
                    int qg = qbase + qf * 16 + l15;
                    if (k0 + 63 > qbase + qf * 16) {   // diagonal tile: apply mask
                        for (int kf = 0; kf < 4; ++kf)
                            for (int r = 0; r < 4; ++r)
                                if (k0 + kf * 16 + quad * 4 + r > qg)
                                    s[kf][qf][r] = -1e30f;
                    }
                    // max via fmaxf triples (v_max3 fusion)
                    float t0 = fmaxf(fmaxf(s[0][qf][0], s[0][qf][1]),
                                     fmaxf(s[0][qf][2], s[0][qf][3]));
                    float t1 = fmaxf(fmaxf(s[1][qf][0], s[1][qf][1]),
                                     fmaxf(s[1][qf][2], s[1][qf][3]));
                    float t2 = fmaxf(fmaxf(s[2][qf][0], s[2][qf][1]),
                                     fmaxf(s[2][qf][2], s[2][qf][3]));
                    float t3 = fmaxf(fmaxf(s[3][qf][0], s[3][qf][1]),
                                     fmaxf(s[3][qf][2], s[3][qf][3]));
                    float rmax = fmaxf(fmaxf(t0, t1), fmaxf(t2, t3));
                    rmax = fmaxf(rmax, __shfl_xor(rmax, 16, 64));
                    rmax = fmaxf(rmax, __shfl_xor(rmax, 32, 64));
                    // T13 defer-max: skip rescale unless some row grew > +8
                    if (!__all(rmax <= m_i[qf] + 8.0f)) {
                        float mn = fmaxf(m_i[qf], rmax);
                        float alpha = exp2a(m_i[qf] - mn);
                        m_i[qf] = mn;
                        l_i[qf] *= alpha;
                        for (int dt = 0; dt < 4; ++dt)
                            for (int r = 0; r < 4; ++r) o_acc[dt][qf][r] *= alpha;
                    }
                    float mref = m_i[qf];
                    float psum = 0.f;
                    for (int kf = 0; kf < 4; ++kf)
                        for (int r = 0; r < 4; ++r) {
                            float p = exp2a(s[kf][qf][r] - mref);
                            s[kf][qf][r] = p;
                            psum += p;
                        }
                    psum += __shfl_xor(psum, 16, 64);
                    psum += __shfl_xor(psum, 32, 64);
                    l_i[qf] += psum;
                    for (int kf = 0; kf < 4; ++kf) {   // P^T -> LDS (uint2)
                        uint2 w;
                        w.x = cvtpk(s[kf][qf][0], s[kf][qf][1]);
                        w.y = cvtpk(s[kf][qf][2], s[kf][qf][3]);
                        *(uint2*)(&pw[(qf * 16 + l15) * 72 + kf * 16 + quad * 4]) = w;
                    }
                }
                // O^T += V^T P^T
                for (int ks = 0; ks < 2; ++ks) {
                    short8 pfr[2], vfr[4];
                    for (int qf = 0; qf < 2; ++qf)
                        pfr[qf] = *(const short8*)(&pw[(qf * 16 + l15) * 72
                                                       + ks * 32 + quad * 8]);
                    for (int dt = 0; dt < 4; ++dt)
                        vfr[dt] = *(const short8*)(&vsb[(dt * 16 + l15) * 64
                                      + (((ks * 4 + quad) ^ (l15 & 7)) * 8)]);
                    for (int dt = 0; dt < 4; ++dt)
                        for (int qf = 0; qf < 2; ++qf)
                            o_acc[dt][qf] = __builtin_amdgcn_mfma_f32_16x16x32_bf16(
                                                vfr[dt], pfr[qf], o_acc[dt][qf], 0, 0, 0);
                }
            }
            bufc ^= 1;
        }

        // O^T C-layout: q = lane&15, d = quad*4+r (within dt)
        for (int qf = 0; qf < 2; ++qf) {
            float rl = 1.f / l_i[qf];
            int q = qbase + qf * 16 + l15;
            for (int dt = 0; dt < 4; ++dt) {
                uint2 w;
                w.x = cvtpk(o_acc[dt][qf][0] * rl, o_acc[dt][qf][1] * rl);
                w.y = cvtpk(o_acc[dt][qf][2] * rl, o_acc[dt][qf][3] * rl);
                *(uint2*)(&Ob[(size_t)(b * SEQ + q) * MODEL_DIM
                              + h * HDIM + dt * 16 + quad * 4]) = w;
            }
        }
    }
}

// --------------------------------------------------------------------- launcher
extern "C" void kernel_launch(void* const* d_in, const int* in_sizes, int n_in,
                              void* d_out, int out_size, void* d_ws, size_t ws_size,
                              hipStream_t stream) {
    const float* X  = (const float*)d_in[0];
    const float* Wq = (const float*)d_in[1];
    const float* bq = (const float*)d_in[2];
    const float* Wk = (const float*)d_in[3];
    const float* bk = (const float*)d_in[4];
    const float* Wv = (const float*)d_in[5];
    const float* bv = (const float*)d_in[6];
    const float* Wo = (const float*)d_in[7];
    const float* bo = (const float*)d_in[8];
    float* out = (float*)d_out;

    // ws: [Xb/Ob 16.78M][Wt 8.39M][Qb 16.78M][Kb 16.78M][unused][VT 16.78M]
    char* ws = (char*)d_ws;
    u16* Xb   = (u16*)ws;                       // aliased by Ob after QKV GEMM
    u16* Ob   = (u16*)ws;
    u16* Wt   = (u16*)(ws + 16777216);
    u16* Qb   = (u16*)(ws + 25165824);
    u16* Kb   = (u16*)(ws + 41943040);
    u32* VT32 = (u32*)(ws + 75497472);

    prep_k<<<dim3(12288), dim3(256), 0, stream>>>(X, Xb, Wq, Wk, Wv, Wo, Wt);
    gemm128_k<0><<<dim3(64, 24), dim3(256), 0, stream>>>(Xb, Wt, Qb, Kb, VT32,
                                                         nullptr, bq, bk, bv, nullptr);
    attn_k<<<dim3(8, 16, 4), dim3(256), 0, stream>>>(Qb, Kb, VT32, Ob);
    gemm128_k<1><<<dim3(64, 8), dim3(256), 0, stream>>>(Ob, Wt, nullptr, nullptr,
                                                        nullptr, out,
                                                        nullptr, nullptr, nullptr, bo);
}